// Round 1
// baseline (1334.031 us; speedup 1.0000x reference)
//
#include <hip/hip_runtime.h>
#include <stdint.h>

// ---------------------------------------------------------------------------
// DecoderRNN: 3-layer GRU (B=256, T=512, IN=64, H=128) + FC(128->6)
// Phased: [gemm gx0][scan L0][gemm gx1][scan L1][gemm gx2][scan L2+FC]
// ---------------------------------------------------------------------------

#define B_   256
#define T_   512
#define IN_  64
#define H_   128
#define G_   384   // 3*H

typedef short bf16x8 __attribute__((ext_vector_type(8)));
typedef float f32x4  __attribute__((ext_vector_type(4)));

__device__ __forceinline__ unsigned short f2bf(float f) {
  union { float f; unsigned u; } v; v.f = f;
  unsigned u = v.u;
  u += 0x7fffu + ((u >> 16) & 1u);   // RNE
  return (unsigned short)(u >> 16);
}
__device__ __forceinline__ float bf2f(unsigned short h) {
  union { unsigned u; float f; } v; v.u = ((unsigned)h) << 16; return v.f;
}

// ---------------------------------------------------------------------------
// GEMM: gx[(t*256+b)*384 + g] = sum_k A[m][k] * W[g][k]   (bf16 MFMA, f32 acc)
//   AF32 (layer0): A = x (f32), m = b*512+t, K=64
//   !AF32        : A = h_seq (bf16), m = t*256+b, K=128
// Block: 128 rows x 384 cols, 512 threads (8 waves: 2 row-groups x 4 col-groups)
// ---------------------------------------------------------------------------
template <int K, bool AF32>
__global__ __launch_bounds__(512) void gemm_gx(const void* __restrict__ Ap,
                                               const float* __restrict__ W,
                                               unsigned short* __restrict__ gx) {
  __shared__ __align__(16) unsigned short lA[128 * K];
  __shared__ __align__(16) unsigned short lW[G_ * K];
  const int tid = threadIdx.x;
  const int m0 = blockIdx.x * 128;

  // ---- stage A -> LDS bf16 (swizzled: byte ^= (row&7)<<4) ----
  if (AF32) {
    const float* A = (const float*)Ap;
    const int nch = 128 * K / 4;
    for (int c = tid; c < nch; c += 512) {
      int row = c / (K / 4), kq = c - row * (K / 4);
      float4 v = *(const float4*)(A + (size_t)(m0 + row) * K + kq * 4);
      unsigned long long pk = (unsigned long long)f2bf(v.x) |
                              ((unsigned long long)f2bf(v.y) << 16) |
                              ((unsigned long long)f2bf(v.z) << 32) |
                              ((unsigned long long)f2bf(v.w) << 48);
      unsigned byte = ((unsigned)(row * K + kq * 4) * 2u) ^ (((unsigned)row & 7u) << 4);
      *(unsigned long long*)((char*)lA + byte) = pk;
    }
  } else {
    const unsigned short* A = (const unsigned short*)Ap;
    const int nch = 128 * K / 8;
    for (int c = tid; c < nch; c += 512) {
      int row = c / (K / 8), ko = c - row * (K / 8);
      bf16x8 v = *(const bf16x8*)(A + (size_t)(m0 + row) * K + ko * 8);
      unsigned byte = ((unsigned)(row * K + ko * 8) * 2u) ^ (((unsigned)row & 7u) << 4);
      *(bf16x8*)((char*)lA + byte) = v;
    }
  }
  // ---- stage W -> LDS bf16 (swizzled) ----
  {
    const int nch = G_ * K / 4;
    for (int c = tid; c < nch; c += 512) {
      int g = c / (K / 4), kq = c - g * (K / 4);
      float4 v = *(const float4*)(W + (size_t)g * K + kq * 4);
      unsigned long long pk = (unsigned long long)f2bf(v.x) |
                              ((unsigned long long)f2bf(v.y) << 16) |
                              ((unsigned long long)f2bf(v.z) << 32) |
                              ((unsigned long long)f2bf(v.w) << 48);
      unsigned byte = ((unsigned)(g * K + kq * 4) * 2u) ^ (((unsigned)g & 7u) << 4);
      *(unsigned long long*)((char*)lW + byte) = pk;
    }
  }
  __syncthreads();

  const int l = tid & 63, w = tid >> 6;
  const int rg = w >> 2, cg = w & 3;  // 2 row-groups x 4 col-groups
  const int lr = l & 15, g4 = l >> 4;

  f32x4 acc[4][6];
#pragma unroll
  for (int i = 0; i < 4; ++i)
#pragma unroll
    for (int j = 0; j < 6; ++j) acc[i][j] = (f32x4){0.f, 0.f, 0.f, 0.f};

#pragma unroll
  for (int ks = 0; ks < K / 32; ++ks) {
    bf16x8 a[4];
#pragma unroll
    for (int i = 0; i < 4; ++i) {
      int row = (rg * 4 + i) * 16 + lr;
      unsigned byte = ((unsigned)(row * K + ks * 32 + g4 * 8) * 2u) ^ (((unsigned)row & 7u) << 4);
      a[i] = *(const bf16x8*)((const char*)lA + byte);
    }
#pragma unroll
    for (int j = 0; j < 6; ++j) {
      int g = (cg * 6 + j) * 16 + lr;
      unsigned byte = ((unsigned)(g * K + ks * 32 + g4 * 8) * 2u) ^ (((unsigned)g & 7u) << 4);
      bf16x8 bfr = *(const bf16x8*)((const char*)lW + byte);
#pragma unroll
      for (int i = 0; i < 4; ++i)
        acc[i][j] = __builtin_amdgcn_mfma_f32_16x16x32_bf16(a[i], bfr, acc[i][j], 0, 0, 0);
    }
  }

  // ---- write gx bf16; C layout: col = lane&15, row = (lane>>4)*4 + reg ----
#pragma unroll
  for (int i = 0; i < 4; ++i)
#pragma unroll
    for (int j = 0; j < 6; ++j)
#pragma unroll
      for (int r = 0; r < 4; ++r) {
        int m = m0 + (rg * 4 + i) * 16 + g4 * 4 + r;
        int g = (cg * 6 + j) * 16 + lr;
        int t, b;
        if (AF32) { t = m & 511; b = m >> 9; } else { t = m >> 8; b = m & 255; }
        gx[(size_t)(t * 256 + b) * G_ + g] = f2bf(acc[i][j][r]);
      }
}

// ---------------------------------------------------------------------------
// GRU scan: 64 blocks x 4 batch rows, 512 threads (8 waves).
// W_hh fragments held in registers for all 512 steps. h carry path fp32/thread.
// Wave w owns gate col-tiles {w, w+8, w+16} = hcols [16w,16w+16) of r,z,n.
// Thread (w,l): batch = l>>4, hcol = 16w + (l&15).
// ---------------------------------------------------------------------------
template <int DOSEQ, int DOFC>
__global__ __launch_bounds__(512) void gru_scan(
    const unsigned short* __restrict__ gx,   // [T][256][384] bf16
    const float* __restrict__ Whh,           // [384][128]
    const float* __restrict__ bih,           // [384]
    const float* __restrict__ bhh,           // [384]
    unsigned short* __restrict__ hseq,       // [T][256][128] bf16 (if DOSEQ)
    const float* __restrict__ fcw,           // [6][128] (if DOFC)
    const float* __restrict__ fcb,           // [6]
    float* __restrict__ out) {               // [256][6]
  __shared__ __align__(16) unsigned short lh[2][2048];   // [16][128] bf16, swizzled
  __shared__ __align__(16) unsigned short lgx[2][1536];  // [4][384] bf16 tile

  const int tid = threadIdx.x, l = tid & 63, w = tid >> 6;
  const int lr = l & 15, g4 = l >> 4;
  const int b0 = blockIdx.x * 4;
  const int batch = g4;                 // 0..3
  const int hcol = w * 16 + lr;         // 0..127

  // zero h buffers (rows 4..15 stay zero forever)
  for (int i = tid; i < 4096; i += 512) ((unsigned short*)lh)[i] = 0;

  // biases
  const float c_r  = bih[hcol]           + bhh[hcol];
  const float c_z  = bih[128 + hcol]     + bhh[128 + hcol];
  const float c_n1 = bih[256 + hcol];
  const float c_n2 = bhh[256 + hcol];

  // ---- preload W_hh fragments into registers (12 frags = 48 VGPR) ----
  bf16x8 Bf[3][4];
#pragma unroll
  for (int ci = 0; ci < 3; ++ci) {
    int gcol = (w + ci * 8) * 16 + lr;
#pragma unroll
    for (int ks = 0; ks < 4; ++ks) {
      const float* p = Whh + (size_t)gcol * H_ + ks * 32 + g4 * 8;
      float4 v0 = *(const float4*)p;
      float4 v1 = *(const float4*)(p + 4);
      bf16x8 f;
      f[0] = (short)f2bf(v0.x); f[1] = (short)f2bf(v0.y);
      f[2] = (short)f2bf(v0.z); f[3] = (short)f2bf(v0.w);
      f[4] = (short)f2bf(v1.x); f[5] = (short)f2bf(v1.y);
      f[6] = (short)f2bf(v1.z); f[7] = (short)f2bf(v1.w);
      Bf[ci][ks] = f;
    }
  }

  // ---- prefetch gx tile t=0 into lgx[0] ----
  const bool pfa = tid < 384;
  if (pfa) {
    unsigned long long v =
        *(const unsigned long long*)((const char*)gx + (size_t)b0 * G_ * 2 + tid * 8);
    *(unsigned long long*)((char*)&lgx[0][0] + tid * 8) = v;
  }
  __syncthreads();

  float hreg = 0.f;

  for (int t = 0; t < T_; ++t) {
    const int cur = t & 1, nxt = cur ^ 1;
    const int tp1 = (t + 1 < T_) ? t + 1 : (T_ - 1);

    // issue prefetch of gx(t+1) early (latency hides under MFMA)
    unsigned long long pfv = 0;
    if (pfa)
      pfv = *(const unsigned long long*)((const char*)gx +
            ((size_t)(tp1 * 256 + b0) * G_) * 2 + tid * 8);

    // A fragments from swizzled h LDS (row = lane&15; rows>=4 are zero)
    bf16x8 a[4];
#pragma unroll
    for (int ks = 0; ks < 4; ++ks) {
      unsigned byte = ((unsigned)(lr * 256 + ks * 64 + g4 * 16)) ^ (((unsigned)lr & 7u) << 4);
      a[ks] = *(const bf16x8*)((const char*)lh[cur] + byte);
    }

    f32x4 aR = (f32x4){0.f, 0.f, 0.f, 0.f};
    f32x4 aZ = (f32x4){0.f, 0.f, 0.f, 0.f};
    f32x4 aN = (f32x4){0.f, 0.f, 0.f, 0.f};
#pragma unroll
    for (int ks = 0; ks < 4; ++ks) {
      aR = __builtin_amdgcn_mfma_f32_16x16x32_bf16(a[ks], Bf[0][ks], aR, 0, 0, 0);
      aZ = __builtin_amdgcn_mfma_f32_16x16x32_bf16(a[ks], Bf[1][ks], aZ, 0, 0, 0);
      aN = __builtin_amdgcn_mfma_f32_16x16x32_bf16(a[ks], Bf[2][ks], aN, 0, 0, 0);
    }

    // redistribute acc -> all 64 lanes: value D[m=batch][n=l&15] sits at
    // lane (l&15), reg = batch.  4x shfl + select per gate.
    float hWr, hWz, hWn;
    {
      float y0 = __shfl(aR[0], lr, 64), y1 = __shfl(aR[1], lr, 64);
      float y2 = __shfl(aR[2], lr, 64), y3 = __shfl(aR[3], lr, 64);
      hWr = batch == 0 ? y0 : batch == 1 ? y1 : batch == 2 ? y2 : y3;
    }
    {
      float y0 = __shfl(aZ[0], lr, 64), y1 = __shfl(aZ[1], lr, 64);
      float y2 = __shfl(aZ[2], lr, 64), y3 = __shfl(aZ[3], lr, 64);
      hWz = batch == 0 ? y0 : batch == 1 ? y1 : batch == 2 ? y2 : y3;
    }
    {
      float y0 = __shfl(aN[0], lr, 64), y1 = __shfl(aN[1], lr, 64);
      float y2 = __shfl(aN[2], lr, 64), y3 = __shfl(aN[3], lr, 64);
      hWn = batch == 0 ? y0 : batch == 1 ? y1 : batch == 2 ? y2 : y3;
    }

    const float gxr = bf2f(lgx[cur][batch * G_ + hcol]);
    const float gxz = bf2f(lgx[cur][batch * G_ + 128 + hcol]);
    const float gxn = bf2f(lgx[cur][batch * G_ + 256 + hcol]);

    const float rg = 1.f / (1.f + __expf(-(gxr + hWr + c_r)));
    const float zg = 1.f / (1.f + __expf(-(gxz + hWz + c_z)));
    const float nx = gxn + c_n1 + rg * (hWn + c_n2);
    const float ng = 1.f - 2.f / (__expf(2.f * nx) + 1.f);
    hreg = (1.f - zg) * ng + zg * hreg;   // carry path stays fp32

    const unsigned short hb = f2bf(hreg);
    *(unsigned short*)((char*)lh[nxt] +
        (((unsigned)(batch * 256 + hcol * 2)) ^ ((unsigned)batch << 4))) = hb;
    if (DOSEQ)
      hseq[(size_t)(t * 256 + b0 + batch) * H_ + hcol] = hb;

    // land prefetched gx(t+1)
    if (pfa) *(unsigned long long*)((char*)&lgx[nxt][0] + tid * 8) = pfv;

    __syncthreads();
  }

  if (DOFC) {
    float* sc = (float*)&lgx[0][0];
    sc[batch * H_ + hcol] = hreg;
    __syncthreads();
    if (tid < 24) {
      int b = tid / 6, c = tid - b * 6;
      float s = fcb[c];
      for (int k = 0; k < H_; ++k) s += sc[b * H_ + k] * fcw[c * H_ + k];
      out[(size_t)(b0 + b) * 6 + c] = s;
    }
  }
}

// ---------------------------------------------------------------------------
extern "C" void kernel_launch(void* const* d_in, const int* in_sizes, int n_in,
                              void* d_out, int out_size, void* d_ws, size_t ws_size,
                              hipStream_t stream) {
  const float* x     = (const float*)d_in[0];  // [256][512][64]
  const float* w_ih0 = (const float*)d_in[1];  // [384][64]
  const float* w_ih1 = (const float*)d_in[2];  // [384][128]
  const float* w_ih2 = (const float*)d_in[3];  // [384][128]
  const float* w_hh  = (const float*)d_in[4];  // [3][384][128]
  const float* b_ih  = (const float*)d_in[5];  // [3][384]
  const float* b_hh  = (const float*)d_in[6];  // [3][384]
  const float* fc_w  = (const float*)d_in[7];  // [6][128]
  const float* fc_b  = (const float*)d_in[8];  // [6]
  float* out = (float*)d_out;                  // [256][6]

  unsigned short* gxb  = (unsigned short*)d_ws;                    // 96 MB
  unsigned short* hseq = gxb + (size_t)T_ * B_ * G_;               // 32 MB

  // layer 0
  gemm_gx<64, true><<<1024, 512, 0, stream>>>((const void*)x, w_ih0, gxb);
  gru_scan<1, 0><<<64, 512, 0, stream>>>(gxb, w_hh, b_ih, b_hh, hseq,
                                         nullptr, nullptr, nullptr);
  // layer 1
  gemm_gx<128, false><<<1024, 512, 0, stream>>>((const void*)hseq, w_ih1, gxb);
  gru_scan<1, 0><<<64, 512, 0, stream>>>(gxb, w_hh + 1 * G_ * H_, b_ih + G_,
                                         b_hh + G_, hseq, nullptr, nullptr, nullptr);
  // layer 2 (+FC fused)
  gemm_gx<128, false><<<1024, 512, 0, stream>>>((const void*)hseq, w_ih2, gxb);
  gru_scan<0, 1><<<64, 512, 0, stream>>>(gxb, w_hh + 2 * G_ * H_, b_ih + 2 * G_,
                                         b_hh + 2 * G_, nullptr, fc_w, fc_b, out);
}

// Round 2
// 1330.427 us; speedup vs baseline: 1.0027x; 1.0027x over previous
//
#include <hip/hip_runtime.h>
#include <stdint.h>

// ---------------------------------------------------------------------------
// DecoderRNN: 3-layer GRU (B=256, T=512, IN=64, H=128) + FC(128->6)
// Phased: [gemm gx0][scan L0][gemm gx1][scan L1][gemm gx2][scan L2+FC]
// R2: scan uses global_load_lds 4-ring + counted vmcnt + raw s_barrier
//     (T3/T4 pattern); gemm gets LDS-transpose coalesced epilogue.
// ---------------------------------------------------------------------------

#define B_   256
#define T_   512
#define IN_  64
#define H_   128
#define G_   384   // 3*H

typedef short bf16x8 __attribute__((ext_vector_type(8)));
typedef float f32x4  __attribute__((ext_vector_type(4)));
typedef unsigned long long u64x2 __attribute__((ext_vector_type(2)));

__device__ __forceinline__ unsigned short f2bf(float f) {
  union { float f; unsigned u; } v; v.f = f;
  unsigned u = v.u;
  u += 0x7fffu + ((u >> 16) & 1u);   // RNE
  return (unsigned short)(u >> 16);
}
__device__ __forceinline__ float bf2f(unsigned short h) {
  union { unsigned u; float f; } v; v.u = ((unsigned)h) << 16; return v.f;
}

__device__ __forceinline__ void gload16(const void* g, void* l) {
  __builtin_amdgcn_global_load_lds(
      (const __attribute__((address_space(1))) void*)g,
      (__attribute__((address_space(3))) void*)l, 16, 0, 0);
}

// ---------------------------------------------------------------------------
// GEMM: gx[(t*256+b)*384 + g] = sum_k A[m][k] * W[g][k]   (bf16 MFMA, f32 acc)
//   AF32 (layer0): A = x (f32), m = b*512+t, K=64
//   !AF32        : A = h_seq (bf16), m = t*256+b, K=128
// Block: 128 rows x 384 cols, 512 threads.  Epilogue: LDS transpose (2 half-
// passes, row stride 776 B -> conflict-free stores) + coalesced b128 writes.
// ---------------------------------------------------------------------------
template <int K, bool AF32>
__global__ __launch_bounds__(512) void gemm_gx(const void* __restrict__ Ap,
                                               const float* __restrict__ W,
                                               unsigned short* __restrict__ gx) {
  __shared__ __align__(16) unsigned short smem[(128 + G_) * K];
  unsigned short* lA = smem;
  unsigned short* lW = smem + 128 * K;
  const int tid = threadIdx.x;
  const int m0 = blockIdx.x * 128;

  // ---- stage A -> LDS bf16 (swizzled: byte ^= (row&7)<<4) ----
  if (AF32) {
    const float* A = (const float*)Ap;
    const int nch = 128 * K / 4;
    for (int c = tid; c < nch; c += 512) {
      int row = c / (K / 4), kq = c - row * (K / 4);
      float4 v = *(const float4*)(A + (size_t)(m0 + row) * K + kq * 4);
      unsigned long long pk = (unsigned long long)f2bf(v.x) |
                              ((unsigned long long)f2bf(v.y) << 16) |
                              ((unsigned long long)f2bf(v.z) << 32) |
                              ((unsigned long long)f2bf(v.w) << 48);
      unsigned byte = ((unsigned)(row * K + kq * 4) * 2u) ^ (((unsigned)row & 7u) << 4);
      *(unsigned long long*)((char*)lA + byte) = pk;
    }
  } else {
    const unsigned short* A = (const unsigned short*)Ap;
    const int nch = 128 * K / 8;
    for (int c = tid; c < nch; c += 512) {
      int row = c / (K / 8), ko = c - row * (K / 8);
      bf16x8 v = *(const bf16x8*)(A + (size_t)(m0 + row) * K + ko * 8);
      unsigned byte = ((unsigned)(row * K + ko * 8) * 2u) ^ (((unsigned)row & 7u) << 4);
      *(bf16x8*)((char*)lA + byte) = v;
    }
  }
  // ---- stage W -> LDS bf16 (swizzled) ----
  {
    const int nch = G_ * K / 4;
    for (int c = tid; c < nch; c += 512) {
      int g = c / (K / 4), kq = c - g * (K / 4);
      float4 v = *(const float4*)(W + (size_t)g * K + kq * 4);
      unsigned long long pk = (unsigned long long)f2bf(v.x) |
                              ((unsigned long long)f2bf(v.y) << 16) |
                              ((unsigned long long)f2bf(v.z) << 32) |
                              ((unsigned long long)f2bf(v.w) << 48);
      unsigned byte = ((unsigned)(g * K + kq * 4) * 2u) ^ (((unsigned)g & 7u) << 4);
      *(unsigned long long*)((char*)lW + byte) = pk;
    }
  }
  __syncthreads();

  const int l = tid & 63, w = tid >> 6;
  const int rg = w >> 2, cg = w & 3;  // 2 row-groups x 4 col-groups
  const int lr = l & 15, g4 = l >> 4;

  f32x4 acc[4][6];
#pragma unroll
  for (int i = 0; i < 4; ++i)
#pragma unroll
    for (int j = 0; j < 6; ++j) acc[i][j] = (f32x4){0.f, 0.f, 0.f, 0.f};

#pragma unroll
  for (int ks = 0; ks < K / 32; ++ks) {
    bf16x8 a[4];
#pragma unroll
    for (int i = 0; i < 4; ++i) {
      int row = (rg * 4 + i) * 16 + lr;
      unsigned byte = ((unsigned)(row * K + ks * 32 + g4 * 8) * 2u) ^ (((unsigned)row & 7u) << 4);
      a[i] = *(const bf16x8*)((const char*)lA + byte);
    }
#pragma unroll
    for (int j = 0; j < 6; ++j) {
      int g = (cg * 6 + j) * 16 + lr;
      unsigned byte = ((unsigned)(g * K + ks * 32 + g4 * 8) * 2u) ^ (((unsigned)g & 7u) << 4);
      bf16x8 bfr = *(const bf16x8*)((const char*)lW + byte);
#pragma unroll
      for (int i = 0; i < 4; ++i)
        acc[i][j] = __builtin_amdgcn_mfma_f32_16x16x32_bf16(a[i], bfr, acc[i][j], 0, 0, 0);
    }
  }

  // ---- epilogue: LDS transpose (2 half-passes of 64 rows), coalesced write.
  // lC row stride = 388 u16 = 776 B (194 dwords, %32 == 2 -> store pattern
  // (mloc*2 + g/2) covers 32 distinct banks per wave-instr: conflict-free).
  unsigned short* lC = smem;
#pragma unroll
  for (int half = 0; half < 2; ++half) {
    __syncthreads();
    if (rg == half) {
#pragma unroll
      for (int i = 0; i < 4; ++i)
#pragma unroll
        for (int j = 0; j < 6; ++j)
#pragma unroll
          for (int r = 0; r < 4; ++r) {
            int mloc = i * 16 + g4 * 4 + r;                 // 0..63
            int g = (cg * 6 + j) * 16 + lr;                 // 0..383
            lC[mloc * 388 + g] = f2bf(acc[i][j][r]);
          }
    }
    __syncthreads();
    // 64 rows x 768 B = 3072 x 16B chunks; global address linear in chunk idx
    for (int it = 0; it < 6; ++it) {
      int c = tid + it * 512;             // 0..3071
      int mloc = c / 48, cb = c - mloc * 48;
      unsigned long long lo =
          *(const unsigned long long*)((const char*)lC + mloc * 776 + cb * 16);
      unsigned long long hi =
          *(const unsigned long long*)((const char*)lC + mloc * 776 + cb * 16 + 8);
      int m = m0 + half * 64 + mloc;
      int row;
      if (AF32) { int t = m & 511, b = m >> 9; row = t * 256 + b; }
      else      { row = m; }
      u64x2 v; v[0] = lo; v[1] = hi;
      *(u64x2*)((char*)gx + (size_t)row * (G_ * 2) + cb * 16) = v;
    }
  }
}

// ---------------------------------------------------------------------------
// GRU scan: 64 blocks x 4 batch rows, 512 threads (8 waves).
// W_hh fragments in registers all 512 steps; h carry fp32/thread.
// gx staged through a 4-deep LDS ring via global_load_lds (waves 0..2, 16B/lane,
// 3 wave-instrs per 3072B tile).  Per-step sync: counted vmcnt (keeps 2 tile
// loads + newest hseq store in flight) + lgkmcnt(0) + RAW s_barrier -- never
// vmcnt(0) in the loop (T3/T4).
// ---------------------------------------------------------------------------
template <int DOSEQ, int DOFC>
__global__ __launch_bounds__(512) void gru_scan(
    const unsigned short* __restrict__ gx,   // [T][256][384] bf16
    const float* __restrict__ Whh,           // [384][128]
    const float* __restrict__ bih,           // [384]
    const float* __restrict__ bhh,           // [384]
    unsigned short* __restrict__ hseq,       // [T][256][128] bf16 (if DOSEQ)
    const float* __restrict__ fcw,           // [6][128] (if DOFC)
    const float* __restrict__ fcb,           // [6]
    float* __restrict__ out) {               // [256][6]
  __shared__ __align__(16) unsigned short lh[2][2048];   // [16][128] bf16, swizzled
  __shared__ __align__(16) unsigned short lgx[4][1536];  // ring: 4 x [4][384] bf16

  const int tid = threadIdx.x, l = tid & 63, w = tid >> 6;
  const int lr = l & 15, g4 = l >> 4;
  const int b0 = blockIdx.x * 4;
  const int batch = g4;                 // 0..3
  const int hcol = w * 16 + lr;         // 0..127

  // zero h buffers (rows 4..15 stay zero forever)
  for (int i = tid; i < 4096; i += 512) ((unsigned short*)lh)[i] = 0;

  // biases
  const float c_r  = bih[hcol]           + bhh[hcol];
  const float c_z  = bih[128 + hcol]     + bhh[128 + hcol];
  const float c_n1 = bih[256 + hcol];
  const float c_n2 = bhh[256 + hcol];

  // ---- preload W_hh fragments into registers (12 frags = 48 VGPR) ----
  bf16x8 Bf[3][4];
#pragma unroll
  for (int ci = 0; ci < 3; ++ci) {
    int gcol = (w + ci * 8) * 16 + lr;
#pragma unroll
    for (int ks = 0; ks < 4; ++ks) {
      const float* p = Whh + (size_t)gcol * H_ + ks * 32 + g4 * 8;
      float4 v0 = *(const float4*)p;
      float4 v1 = *(const float4*)(p + 4);
      bf16x8 f;
      f[0] = (short)f2bf(v0.x); f[1] = (short)f2bf(v0.y);
      f[2] = (short)f2bf(v0.z); f[3] = (short)f2bf(v0.w);
      f[4] = (short)f2bf(v1.x); f[5] = (short)f2bf(v1.y);
      f[6] = (short)f2bf(v1.z); f[7] = (short)f2bf(v1.w);
      Bf[ci][ks] = f;
    }
  }

  // Drain everything (Bf/bias loads, lh zero-writes) so in-loop vmcnt counting
  // sees only ring loads + hseq stores. Then issue ring loads for t=0,1,2.
  __syncthreads();
  if (w < 3) {
#pragma unroll
    for (int p = 0; p < 3; ++p) {
      const char* src = (const char*)gx + ((size_t)(p * 256 + b0) * G_) * 2 + (size_t)tid * 16;
      gload16(src, (char*)&lgx[p][0] + w * 1024);
    }
    asm volatile("s_waitcnt vmcnt(2)" ::: "memory");  // t=0 tile landed
  }
  asm volatile("s_waitcnt lgkmcnt(0)" ::: "memory");
  __builtin_amdgcn_s_barrier();
  __builtin_amdgcn_sched_barrier(0);

  float hreg = 0.f;

  for (int t = 0; t < T_; ++t) {
    const int cur = t & 1, nxt = cur ^ 1;
    const int slot = t & 3;

    // A fragments from swizzled h LDS (row = lane&15; rows>=4 are zero)
    bf16x8 a[4];
#pragma unroll
    for (int ks = 0; ks < 4; ++ks) {
      unsigned byte = ((unsigned)(lr * 256 + ks * 64 + g4 * 16)) ^ (((unsigned)lr & 7u) << 4);
      a[ks] = *(const bf16x8*)((const char*)lh[cur] + byte);
    }
    // gate inputs from ring (issued early to overlap with MFMA)
    const float gxr = bf2f(lgx[slot][batch * G_ + hcol]);
    const float gxz = bf2f(lgx[slot][batch * G_ + 128 + hcol]);
    const float gxn = bf2f(lgx[slot][batch * G_ + 256 + hcol]);

    f32x4 aR = (f32x4){0.f, 0.f, 0.f, 0.f};
    f32x4 aZ = (f32x4){0.f, 0.f, 0.f, 0.f};
    f32x4 aN = (f32x4){0.f, 0.f, 0.f, 0.f};
#pragma unroll
    for (int ks = 0; ks < 4; ++ks) {
      aR = __builtin_amdgcn_mfma_f32_16x16x32_bf16(a[ks], Bf[0][ks], aR, 0, 0, 0);
      aZ = __builtin_amdgcn_mfma_f32_16x16x32_bf16(a[ks], Bf[1][ks], aZ, 0, 0, 0);
      aN = __builtin_amdgcn_mfma_f32_16x16x32_bf16(a[ks], Bf[2][ks], aN, 0, 0, 0);
    }

    // redistribute: D[m=batch][n=lr] lives at lane lr, reg batch
    float hWr, hWz, hWn;
    {
      float y0 = __shfl(aR[0], lr, 64), y1 = __shfl(aR[1], lr, 64);
      float y2 = __shfl(aR[2], lr, 64), y3 = __shfl(aR[3], lr, 64);
      hWr = batch == 0 ? y0 : batch == 1 ? y1 : batch == 2 ? y2 : y3;
    }
    {
      float y0 = __shfl(aZ[0], lr, 64), y1 = __shfl(aZ[1], lr, 64);
      float y2 = __shfl(aZ[2], lr, 64), y3 = __shfl(aZ[3], lr, 64);
      hWz = batch == 0 ? y0 : batch == 1 ? y1 : batch == 2 ? y2 : y3;
    }
    {
      float y0 = __shfl(aN[0], lr, 64), y1 = __shfl(aN[1], lr, 64);
      float y2 = __shfl(aN[2], lr, 64), y3 = __shfl(aN[3], lr, 64);
      hWn = batch == 0 ? y0 : batch == 1 ? y1 : batch == 2 ? y2 : y3;
    }

    const float rg = 1.f / (1.f + __expf(-(gxr + hWr + c_r)));
    const float zg = 1.f / (1.f + __expf(-(gxz + hWz + c_z)));
    const float nx = gxn + c_n1 + rg * (hWn + c_n2);
    const float ng = 1.f - 2.f / (__expf(2.f * nx) + 1.f);
    hreg = (1.f - zg) * ng + zg * hreg;   // carry path stays fp32

    const unsigned short hb = f2bf(hreg);
    *(unsigned short*)((char*)lh[nxt] +
        (((unsigned)(batch * 256 + hcol * 2)) ^ ((unsigned)batch << 4))) = hb;
    if (DOSEQ)
      hseq[(size_t)(t * 256 + b0 + batch) * H_ + hcol] = hb;

    // issue ring load for t+3 into slot (t+3)&3 (free: current slot is t&3,
    // t+1 landed, t+2 in flight)
    if (w < 3) {
      int t3 = t + 3; if (t3 > T_ - 1) t3 = T_ - 1;
      const char* src = (const char*)gx + ((size_t)(t3 * 256 + b0) * G_) * 2 + (size_t)tid * 16;
      gload16(src, (char*)&lgx[(t + 3) & 3][0] + w * 1024);
    }

    __builtin_amdgcn_sched_barrier(0);
    if (w < 3) {
      // DOSEQ: outstanding <= {L(t+2), S(t), L(t+3)} -> L(t+1)+older stores done
      // DOFC : outstanding <= {L(t+2), L(t+3)}       -> L(t+1) done
      asm volatile("s_waitcnt vmcnt(%0)" :: "n"(DOSEQ ? 3 : 2) : "memory");
    }
    asm volatile("s_waitcnt lgkmcnt(0)" ::: "memory");
    __builtin_amdgcn_s_barrier();
    __builtin_amdgcn_sched_barrier(0);
  }

  if (DOFC) {
    __syncthreads();
    float* sc = (float*)&lgx[0][0];
    sc[batch * H_ + hcol] = hreg;
    __syncthreads();
    if (tid < 24) {
      int b = tid / 6, c = tid - b * 6;
      float s = fcb[c];
      for (int k = 0; k < H_; ++k) s += sc[b * H_ + k] * fcw[c * H_ + k];
      out[(size_t)(b0 + b) * 6 + c] = s;
    }
  }
}

// ---------------------------------------------------------------------------
extern "C" void kernel_launch(void* const* d_in, const int* in_sizes, int n_in,
                              void* d_out, int out_size, void* d_ws, size_t ws_size,
                              hipStream_t stream) {
  const float* x     = (const float*)d_in[0];  // [256][512][64]
  const float* w_ih0 = (const float*)d_in[1];  // [384][64]
  const float* w_ih1 = (const float*)d_in[2];  // [384][128]
  const float* w_ih2 = (const float*)d_in[3];  // [384][128]
  const float* w_hh  = (const float*)d_in[4];  // [3][384][128]
  const float* b_ih  = (const float*)d_in[5];  // [3][384]
  const float* b_hh  = (const float*)d_in[6];  // [3][384]
  const float* fc_w  = (const float*)d_in[7];  // [6][128]
  const float* fc_b  = (const float*)d_in[8];  // [6]
  float* out = (float*)d_out;                  // [256][6]

  unsigned short* gxb  = (unsigned short*)d_ws;                    // 96 MB
  unsigned short* hseq = gxb + (size_t)T_ * B_ * G_;               // 32 MB

  // layer 0
  gemm_gx<64, true><<<1024, 512, 0, stream>>>((const void*)x, w_ih0, gxb);
  gru_scan<1, 0><<<64, 512, 0, stream>>>(gxb, w_hh, b_ih, b_hh, hseq,
                                         nullptr, nullptr, nullptr);
  // layer 1
  gemm_gx<128, false><<<1024, 512, 0, stream>>>((const void*)hseq, w_ih1, gxb);
  gru_scan<1, 0><<<64, 512, 0, stream>>>(gxb, w_hh + 1 * G_ * H_, b_ih + G_,
                                         b_hh + G_, hseq, nullptr, nullptr, nullptr);
  // layer 2 (+FC fused)
  gemm_gx<128, false><<<1024, 512, 0, stream>>>((const void*)hseq, w_ih2, gxb);
  gru_scan<0, 1><<<64, 512, 0, stream>>>(gxb, w_hh + 2 * G_ * H_, b_ih + 2 * G_,
                                         b_hh + 2 * G_, nullptr, fc_w, fc_b, out);
}